// Round 10
// baseline (342.971 us; speedup 1.0000x reference)
//
#include <hip/hip_runtime.h>

typedef float v4f __attribute__((ext_vector_type(4)));

#define NPTS    1024
#define MGRID   1024
#define MAXL    320      // compaction capacity (expected ~170, big headroom)
#define UPB     8        // midpoints (u values) per F-table block
#define FSTRIDE 2048     // padded u-stride of the F table
#define CUT     0.32f    // exp(-(x-m)^2/s^2) underflows past |x-m| ~ 0.292
#define HBAND   96       // band half-width: outside |i-j|>96, |out| < 1e-5

// ---------------------------------------------------------------------------
// Ledger: out[b,k,i,j] = B(i-j)*F[b,k](i+j) (R5 factorization).
// Store-rate law (R7/R8/R9): a wave's store throughput is set by whether its
// stream contains loads/compute — pure-store waves 4.8-6.2 TB/s; any wave
// that interleaves loads caps ~2.5-3.8 TB/s, and R9 proved "independent"
// zero stores in a loading wave are dragged down too, not hoisted.
// R10 = three validated pure-role pieces, every byte written exactly once:
//   1. fill_kernel  (R1, pure store): identity planes + outside-window zeros
//      (231 MB @ ~5 TB/s measured in R1)
//   2. f_table_kernel (R5-R9): 557 KB of information, ~4 us
//   3. band2_kernel (R8): the 72 MB of windows, 4 rows/wave hoisted-load
//      batched-store form (3.8 TB/s measured in R8)
// ---------------------------------------------------------------------------

// ============================ kernel 1: structural fill ====================
// Pure store, no loads. grid (256 i-groups, 18 ch, 4 b), wave = one row.
__global__ __launch_bounds__(256)
void fill_kernel(float* __restrict__ out)
{
    const int bx   = blockIdx.x;    // i-group: rows 4*bx .. 4*bx+3
    const int ch   = blockIdx.y;    // channel 0..17
    const int b    = blockIdx.z;    // batch
    const int tid  = threadIdx.x;
    const int w    = tid >> 6;      // wave -> row within group
    const int lane = tid & 63;
    const int i0   = bx * 4;

    // window geometry must match band2_kernel exactly
    const int i = i0 + w;
    int s = (i - HBAND) & ~3;
    s = s < 0 ? 0 : (s > MGRID - 256 ? MGRID - 256 : s);
    const int wstart = s >> 2;      // window start, float4 units

    float* big = out + MGRID;
    const size_t plane = (size_t)MGRID * MGRID;
    v4f* rp = (v4f*)(big + (size_t)b * 18 * plane + (size_t)ch * plane
                         + (size_t)i * MGRID);

    if (ch == 0) {
        // identity row: full 1024 floats (256 float4, 4 per lane)
        #pragma unroll
        for (int it = 0; it < 4; ++it) {
            const int q  = it * 64 + lane;
            const int j0 = q * 4;
            v4f v;
            v.x = (j0 + 0 == i) ? 1.f : 0.f;
            v.y = (j0 + 1 == i) ? 1.f : 0.f;
            v.z = (j0 + 2 == i) ? 1.f : 0.f;
            v.w = (j0 + 3 == i) ? 1.f : 0.f;
            rp[q] = v;
        }
    } else {
        // zero the 192 float4 outside the 64-float4 window
        const v4f zero4 = {0.f, 0.f, 0.f, 0.f};
        #pragma unroll
        for (int it = 0; it < 3; ++it) {
            const int q  = it * 64 + lane;              // 0..191
            const int f4 = (q < wstart) ? q : q + 64;   // skip window
            rp[f4] = zero4;
        }
    }
}

// ============================ kernel 2: F table ============================
// grid (256, 4): 8 u's per block, batch in y. ~3-5 us. (proven R5-R9)
__global__ __launch_bounds__(256)
void f_table_kernel(const float* __restrict__ xz,
                    const float* __restrict__ z,
                    const float* __restrict__ x_grid,
                    const float* __restrict__ log_scale,
                    float* __restrict__ F)
{
    const int ug   = blockIdx.x;        // u-group: u = 8*ug .. 8*ug+7
    const int b    = blockIdx.y;        // batch
    const int tid  = threadIdx.x;
    const int w    = tid >> 6;          // wave 0..3
    const int lane = tid & 63;
    const int u0   = ug * UPB;

    __shared__ float xz_l[MAXL];
    __shared__ v4f   z_l[MAXL * 4];     // 16 floats per point
    __shared__ int   cnts[4];

    const float s2   = __expf(2.0f * log_scale[0]);
    const float ninv = -1.0f / s2;      // exponent coefficient

    // window for this block's midpoint range
    const int  u7  = (u0 + UPB - 1) > 2046 ? 2046 : (u0 + UPB - 1);
    const float m_lo = 0.5f * (x_grid[u0 >> 1] + x_grid[u0 - (u0 >> 1)]);
    const float m_hi = 0.5f * (x_grid[u7 >> 1] + x_grid[u7 - (u7 >> 1)]);
    const float lo = m_lo - CUT, hi = m_hi + CUT;

    // ---- phase 1: predicate + per-wave ballot compaction
    const float* xzb = xz + b * NPTS;
    float xv[4]; unsigned long long msk[4]; int idx[4];
    int base = 0;
    #pragma unroll
    for (int r = 0; r < 4; ++r) {
        const int n = 256 * w + 64 * r + lane;
        xv[r] = xzb[n];
        const bool pred = (xv[r] > lo) && (xv[r] < hi);
        msk[r] = __ballot(pred);
        idx[r] = base + (int)__popcll(msk[r] & ((1ull << lane) - 1ull));
        base += (int)__popcll(msk[r]);
    }
    if (lane == 0) cnts[w] = base;
    __syncthreads();

    int off = 0, total = 0;
    #pragma unroll
    for (int s = 0; s < 4; ++s) { const int c = cnts[s]; if (s < w) off += c; total += c; }
    if (total > MAXL) total = MAXL;

    // ---- phase 2: stage selected points into LDS
    const v4f* zb4 = (const v4f*)(z + (size_t)b * NPTS * 16);
    #pragma unroll
    for (int r = 0; r < 4; ++r) {
        if ((msk[r] >> lane) & 1ull) {
            const int slot = off + idx[r];
            if (slot < MAXL) {
                const int n = 256 * w + 64 * r + lane;
                xz_l[slot] = xv[r];
                #pragma unroll
                for (int q = 0; q < 4; ++q)
                    z_l[slot * 4 + q] = zb4[n * 4 + q];
            }
        }
    }
    __syncthreads();

    // ---- phase 3: thread (ul, kk) accumulates F[b][kk][u0+ul]
    const int ul = tid >> 5;            // 0..7
    const int kk = tid & 31;            // channel slot; active when < 17 (0 = ones)
    const int u  = u0 + ul;
    const int uu = u > 2046 ? 2046 : u;
    const float xm = 0.5f * (x_grid[uu >> 1] + x_grid[uu - (uu >> 1)]);

    const float* zl = (const float*)z_l;
    const int zidx0 = (kk == 0) ? 0 : (kk - 1);
    const bool isone = (kk == 0);

    float acc = 0.0f;
    for (int t = 0; t < total; ++t) {
        const float d = xz_l[t] - xm;
        const float e = __expf(ninv * (d * d));
        const float val = isone ? 1.0f : zl[t * 16 + zidx0];
        acc += e * val;
    }

    if (kk < 17 && u <= 2046)
        F[((b * 17 + kk) << 11) + u] = acc;   // FSTRIDE = 2048
}

// ============================ kernel 3: band emit ==========================
// R8's proven form. Wave-jobs (4 rows each):
//   0..17407 : value planes (68 = 4b x 17vc, 256 row-groups); 32 hoisted
//              loads -> compute -> 4 back-to-back 1KB window stores.
//   17408    : x_grid passthrough.
__global__ __launch_bounds__(256)
void band2_kernel(const float* __restrict__ x_grid,
                  const float* __restrict__ log_scale,
                  const float* __restrict__ F,
                  float* __restrict__ out)
{
    const int job  = blockIdx.x * 4 + (threadIdx.x >> 6);
    const int lane = threadIdx.x & 63;

    float* big = out + MGRID;
    const size_t plane = (size_t)MGRID * MGRID;

    if (job >= 17408) {
        if (job == 17408) {
            #pragma unroll
            for (int q = 0; q < 4; ++q) {
                const int f4i = q * 64 + lane;
                ((v4f*)out)[f4i] = ((const v4f*)x_grid)[f4i];
            }
        }
        return;
    }

    const int p  = job >> 8;          // value-plane 0..67
    const int rg = job & 255;         // row group
    const int b  = p / 17;
    const int vc = p % 17;            // 0 = density (out ch1), 1..16 = ratios
    const int i0 = rg * 4;

    const float s2 = __expf(2.0f * log_scale[0]);
    const float h  = x_grid[1] - x_grid[0];
    const float cB = -(h * h) / (4.0f * s2);

    const float* F0 = F + (b * 17) * FSTRIDE;
    const float* Fk = F0 + vc * FSTRIDE;          // vc=0 -> F0 (density path)
    float* pb = big + (size_t)(b * 18 + 1 + vc) * plane;

    // ---- hoisted loads for 4 rows
    int   st[4];
    float f0v[4][4], fkv[4][4];
    #pragma unroll
    for (int r = 0; r < 4; ++r) {
        const int i = i0 + r;
        int s = (i - HBAND) & ~3;
        s = s < 0 ? 0 : (s > MGRID - 256 ? MGRID - 256 : s);
        st[r] = s;
        const int u = i + s + 4 * lane;           // max 2046 ✓
        #pragma unroll
        for (int l = 0; l < 4; ++l) {
            f0v[r][l] = F0[u + l];
            fkv[r][l] = Fk[u + l];
        }
    }

    // ---- compute 4 rows
    v4f vals[4];
    #pragma unroll
    for (int r = 0; r < 4; ++r) {
        const int i  = i0 + r;
        const int j0 = st[r] + 4 * lane;
        #pragma unroll
        for (int l = 0; l < 4; ++l) {
            const float d = (float)(i - (j0 + l));
            const float B = __expf(cB * d * d);
            if (vc == 0) {
                vals[r][l] = B * f0v[r][l];                       // density
            } else {
                const float den = B * f0v[r][l] + 1e-8f;
                vals[r][l] = (B * fkv[r][l]) * __builtin_amdgcn_rcpf(den);
            }
        }
    }

    // ---- 4 back-to-back 1KB stores
    #pragma unroll
    for (int r = 0; r < 4; ++r)
        *(v4f*)(pb + (size_t)(i0 + r) * MGRID + st[r] + 4 * lane) = vals[r];
}

extern "C" void kernel_launch(void* const* d_in, const int* in_sizes, int n_in,
                              void* d_out, int out_size, void* d_ws, size_t ws_size,
                              hipStream_t stream)
{
    const float* xz = (const float*)d_in[0];
    const float* z  = (const float*)d_in[1];
    const float* xg = (const float*)d_in[2];
    const float* ls = (const float*)d_in[3];
    float* out = (float*)d_out;
    float* F   = (float*)d_ws;          // 4*17*2048*4 B = 557 KB

    // Pure-store structural fill (231 MB), info table (557 KB), band (72 MB).
    fill_kernel   <<<dim3(MGRID / 4, 18, 4), dim3(256), 0, stream>>>(out);
    f_table_kernel<<<dim3(2048 / UPB, 4),    dim3(256), 0, stream>>>(xz, z, xg, ls, F);
    band2_kernel  <<<dim3((17409 + 3) / 4),  dim3(256), 0, stream>>>(xg, ls, F, out);
}

// Round 11
// 294.835 us; speedup vs baseline: 1.1633x; 1.1633x over previous
//
#include <hip/hip_runtime.h>

typedef float v4f __attribute__((ext_vector_type(4)));

#define NPTS    1024
#define MGRID   1024
#define MAXL    320      // compaction capacity (expected ~170, big headroom)
#define UPB     8        // midpoints (u values) per F-table block
#define FSTRIDE 2048     // padded u-stride of the F table
#define CUT     0.32f    // exp(-(x-m)^2/s^2) underflows past |x-m| ~ 0.292
#define HBAND   96       // band half-width: outside |i-j|>96, |out| < 1e-6

// ---------------------------------------------------------------------------
// FINAL structure (= R8, best measured 294.8 us; R9/R10 regressions reverted).
// Math: out[b,k,i,j] = B(i-j) * F[b,k](i+j)  (R5 factorization, exact in R).
// Store-rate law established over R0-R10 on this chip:
//   - full-row LINEAR store streams (memset/fillBuffer-style): 5.5-6.2 TB/s
//   - window-skipping streams: ~2.5-3.2 TB/s EVEN with zero loads (R10)
//   - load-interleaved streams: 1.3-2.7 TB/s; hoisted-load + batched-store
//     recovers to ~3.8 TB/s (R8's band)
// Therefore: memset ALL 302 MB at the linear rate, then rewrite only the
// 72 MB diagonal band (|i-j|<=96; outside it |out| < 1e-6 << tolerance).
// Writing the 231 MB complement instead is slower (R10: holey = 2.3-3.2).
//   1. hipMemsetAsync(302 MB)            ~55 us   [linear rate]
//   2. f_table_kernel (557 KB of info)   ~4 us
//   3. band2_kernel (72 MB windows)      ~19 us   [4 rows/wave, hoisted loads]
// ---------------------------------------------------------------------------

// ============================ kernel 1: F table ============================
// grid (256, 4): 8 u's per block, batch in y. ~3-5 us. (proven R5-R10)
__global__ __launch_bounds__(256)
void f_table_kernel(const float* __restrict__ xz,
                    const float* __restrict__ z,
                    const float* __restrict__ x_grid,
                    const float* __restrict__ log_scale,
                    float* __restrict__ F)
{
    const int ug   = blockIdx.x;        // u-group: u = 8*ug .. 8*ug+7
    const int b    = blockIdx.y;        // batch
    const int tid  = threadIdx.x;
    const int w    = tid >> 6;          // wave 0..3
    const int lane = tid & 63;
    const int u0   = ug * UPB;

    __shared__ float xz_l[MAXL];
    __shared__ v4f   z_l[MAXL * 4];     // 16 floats per point
    __shared__ int   cnts[4];

    const float s2   = __expf(2.0f * log_scale[0]);
    const float ninv = -1.0f / s2;      // exponent coefficient

    // window for this block's midpoint range
    const int  u7  = (u0 + UPB - 1) > 2046 ? 2046 : (u0 + UPB - 1);
    const float m_lo = 0.5f * (x_grid[u0 >> 1] + x_grid[u0 - (u0 >> 1)]);
    const float m_hi = 0.5f * (x_grid[u7 >> 1] + x_grid[u7 - (u7 >> 1)]);
    const float lo = m_lo - CUT, hi = m_hi + CUT;

    // ---- phase 1: predicate + per-wave ballot compaction
    const float* xzb = xz + b * NPTS;
    float xv[4]; unsigned long long msk[4]; int idx[4];
    int base = 0;
    #pragma unroll
    for (int r = 0; r < 4; ++r) {
        const int n = 256 * w + 64 * r + lane;
        xv[r] = xzb[n];
        const bool pred = (xv[r] > lo) && (xv[r] < hi);
        msk[r] = __ballot(pred);
        idx[r] = base + (int)__popcll(msk[r] & ((1ull << lane) - 1ull));
        base += (int)__popcll(msk[r]);
    }
    if (lane == 0) cnts[w] = base;
    __syncthreads();

    int off = 0, total = 0;
    #pragma unroll
    for (int s = 0; s < 4; ++s) { const int c = cnts[s]; if (s < w) off += c; total += c; }
    if (total > MAXL) total = MAXL;

    // ---- phase 2: stage selected points into LDS
    const v4f* zb4 = (const v4f*)(z + (size_t)b * NPTS * 16);
    #pragma unroll
    for (int r = 0; r < 4; ++r) {
        if ((msk[r] >> lane) & 1ull) {
            const int slot = off + idx[r];
            if (slot < MAXL) {
                const int n = 256 * w + 64 * r + lane;
                xz_l[slot] = xv[r];
                #pragma unroll
                for (int q = 0; q < 4; ++q)
                    z_l[slot * 4 + q] = zb4[n * 4 + q];
            }
        }
    }
    __syncthreads();

    // ---- phase 3: thread (ul, kk) accumulates F[b][kk][u0+ul]
    const int ul = tid >> 5;            // 0..7
    const int kk = tid & 31;            // channel slot; active when < 17 (0 = ones)
    const int u  = u0 + ul;
    const int uu = u > 2046 ? 2046 : u;
    const float xm = 0.5f * (x_grid[uu >> 1] + x_grid[uu - (uu >> 1)]);

    const float* zl = (const float*)z_l;
    const int zidx0 = (kk == 0) ? 0 : (kk - 1);
    const bool isone = (kk == 0);

    float acc = 0.0f;
    for (int t = 0; t < total; ++t) {
        const float d = xz_l[t] - xm;
        const float e = __expf(ninv * (d * d));
        const float val = isone ? 1.0f : zl[t * 16 + zidx0];
        acc += e * val;
    }

    if (kk < 17 && u <= 2046)
        F[((b * 17 + kk) << 11) + u] = acc;   // FSTRIDE = 2048
}

// ============================ kernel 2: band emit v2 =======================
// Wave-jobs:
//   0..17407     : value band — 68 planes (4 batches x 17 value chans) x 256
//                  row-groups; each wave does 4 consecutive rows: 32 hoisted
//                  loads -> compute -> 4 back-to-back 1KB stores.
//   17408..17471 : ch0 identity diagonal (4 planes x 16 chunks of 64)
//   17472        : x_grid passthrough
__global__ __launch_bounds__(256)
void band2_kernel(const float* __restrict__ x_grid,
                  const float* __restrict__ log_scale,
                  const float* __restrict__ F,
                  float* __restrict__ out)
{
    const int job  = blockIdx.x * 4 + (threadIdx.x >> 6);
    const int lane = threadIdx.x & 63;

    float* big = out + MGRID;
    const size_t plane = (size_t)MGRID * MGRID;

    if (job >= 17408) {
        if (job < 17472) {
            const int t  = job - 17408;   // 0..63
            const int pc = t >> 4;        // batch
            const int c  = t & 15;
            const int i  = c * 64 + lane;
            big[(size_t)(pc * 18) * plane + (size_t)i * MGRID + i] = 1.0f;
        } else if (job == 17472) {
            #pragma unroll
            for (int q = 0; q < 4; ++q) {
                const int f4i = q * 64 + lane;
                ((v4f*)out)[f4i] = ((const v4f*)x_grid)[f4i];
            }
        }
        return;
    }

    const int p  = job >> 8;          // value-plane 0..67
    const int rg = job & 255;         // row group
    const int b  = p / 17;
    const int vc = p % 17;            // 0 = density (out ch1), 1..16 = ratios
    const int i0 = rg * 4;

    const float s2 = __expf(2.0f * log_scale[0]);
    const float h  = x_grid[1] - x_grid[0];
    const float cB = -(h * h) / (4.0f * s2);

    const float* F0 = F + (b * 17) * FSTRIDE;
    const float* Fk = F0 + vc * FSTRIDE;          // vc=0 -> F0 (density path)
    float* pb = big + (size_t)(b * 18 + 1 + vc) * plane;

    // ---- hoisted loads for 4 rows
    int   st[4];
    float f0v[4][4], fkv[4][4];
    #pragma unroll
    for (int r = 0; r < 4; ++r) {
        const int i = i0 + r;
        int s = (i - HBAND) & ~3;
        s = s < 0 ? 0 : (s > MGRID - 256 ? MGRID - 256 : s);
        st[r] = s;
        const int u = i + s + 4 * lane;           // max 2046 at i=1023 ✓
        #pragma unroll
        for (int l = 0; l < 4; ++l) {
            f0v[r][l] = F0[u + l];
            fkv[r][l] = Fk[u + l];
        }
    }

    // ---- compute 4 rows
    v4f vals[4];
    #pragma unroll
    for (int r = 0; r < 4; ++r) {
        const int i  = i0 + r;
        const int j0 = st[r] + 4 * lane;
        #pragma unroll
        for (int l = 0; l < 4; ++l) {
            const float d = (float)(i - (j0 + l));
            const float B = __expf(cB * d * d);
            if (vc == 0) {
                vals[r][l] = B * f0v[r][l];                       // density
            } else {
                const float den = B * f0v[r][l] + 1e-8f;
                vals[r][l] = (B * fkv[r][l]) * __builtin_amdgcn_rcpf(den);
            }
        }
    }

    // ---- 4 back-to-back 1KB stores
    #pragma unroll
    for (int r = 0; r < 4; ++r)
        *(v4f*)(pb + (size_t)(i0 + r) * MGRID + st[r] + 4 * lane) = vals[r];
}

extern "C" void kernel_launch(void* const* d_in, const int* in_sizes, int n_in,
                              void* d_out, int out_size, void* d_ws, size_t ws_size,
                              hipStream_t stream)
{
    const float* xz = (const float*)d_in[0];
    const float* z  = (const float*)d_in[1];
    const float* xg = (const float*)d_in[2];
    const float* ls = (const float*)d_in[3];
    float* out = (float*)d_out;
    float* F   = (float*)d_ws;          // 4*17*2048*4 B = 557 KB

    // Bulk zero at the proven linear-stream rate (pure store).
    hipMemsetAsync(out, 0, (size_t)out_size, stream);

    // F table (557 KB of real info), then the 72 MB band + diag + x_grid.
    f_table_kernel<<<dim3(2048 / UPB, 4), dim3(256), 0, stream>>>(xz, z, xg, ls, F);
    band2_kernel  <<<dim3((17473 + 3) / 4), dim3(256), 0, stream>>>(xg, ls, F, out);
}